// Round 12
// baseline (308.425 us; speedup 1.0000x reference)
//
#include <hip/hip_runtime.h>
#include <math.h>

#define RL(x) __builtin_amdgcn_readfirstlane(x)

typedef short  s16x8 __attribute__((ext_vector_type(8)));
typedef float  f32x4 __attribute__((ext_vector_type(4)));

__device__ __forceinline__ float relu_(float v) { return v > 0.f ? v : 0.f; }
__device__ __forceinline__ unsigned short f2bf(float f) {
  unsigned u = __float_as_uint(f);
  u += 0x7FFFu + ((u >> 16) & 1u);           // round-to-nearest-even
  return (unsigned short)(u >> 16);
}
__device__ __forceinline__ float bf2f(unsigned short h) {
  return __uint_as_float((unsigned)h << 16);
}

// ---------------------------------------------------------------------------
// Prep: w1 -> bf16 copy, dw1 -> bf16 transpose [n][k], LINT/DLINT transposes,
// |emb|^2, zero SCAL/COUNTS. grid 213.
// ---------------------------------------------------------------------------
__global__ __launch_bounds__(256) void k_prep(
    const float* __restrict__ w1, const float* __restrict__ linw,
    const float* __restrict__ dlinw, const float* __restrict__ emb,
    const float* __restrict__ dw1,
    unsigned short* __restrict__ w1b, float* __restrict__ linT,
    float* __restrict__ dlinT, float* __restrict__ embsq,
    unsigned short* __restrict__ dw1b,
    float* __restrict__ scal, float* __restrict__ counts)
{
  int bid = blockIdx.x, tid = threadIdx.x;
  if (bid < 64) {                      // ---- w1 -> bf16 (no transpose) ----
    #pragma unroll
    for (int j = 0; j < 32; ++j) {
      int idx = bid * 16384 + j * 512 + tid * 2;
      float2 v = *(const float2*)(w1 + idx);
      unsigned pk = ((unsigned)f2bf(v.y) << 16) | (unsigned)f2bf(v.x);
      *(unsigned*)&w1b[idx] = pk;
    }
    return;
  }
  if (bid == 84) {
    if (tid < 2) scal[tid] = 0.f;
    for (int j = tid; j < 512; j += 256) counts[j] = 0.f;
    return;
  }
  if (bid >= 85) {                     // ---- dw1 transpose -> bf16 ----
    __shared__ float tbuf[64 * 65];
    int idx = bid - 85;
    int r0 = (idx >> 6) * 64, c0 = (idx & 63) * 64;
    int lane = tid & 63, grp = tid >> 6;
    for (int pp = 0; pp < 16; ++pp) {
      int rr = pp * 4 + grp;
      tbuf[rr * 65 + lane] = dw1[(size_t)(r0 + rr) * 4096 + c0 + lane];
    }
    __syncthreads();
    for (int pp = 0; pp < 16; ++pp) {
      int cc = pp * 4 + grp;
      dw1b[(size_t)(c0 + cc) * 128 + r0 + lane] = f2bf(tbuf[lane * 65 + cc]);
    }
    return;
  }
  if (bid >= 82) {
    int k = (bid - 82) * 256 + tid;
    const float* e = emb + k * 64;
    float s0 = 0, s1 = 0, s2 = 0, s3 = 0;
    #pragma unroll
    for (int c = 0; c < 64; c += 4) {
      s0 += e[c] * e[c]; s1 += e[c+1] * e[c+1];
      s2 += e[c+2] * e[c+2]; s3 += e[c+3] * e[c+3];
    }
    embsq[k] = (s0 + s1) + (s2 + s3);
    return;
  }
  __shared__ float buf[64 * 65];
  const float* in; float* out; int R, C, tr, tc;
  if (bid < 80) { in = linw;  out = linT;  R = 256; C = 256; tr = (bid - 64) >> 2; tc = (bid - 64) & 3; }
  else          { in = dlinw; out = dlinT; R = 128; C = 128; tr = (bid - 80) >> 1; tc = (bid - 80) & 1; }
  int r0 = tr * 64, c0 = tc * 64;
  int lane = tid & 63, grp = tid >> 6;
  for (int pp = 0; pp < 16; ++pp) {
    int rr = pp * 4 + grp;
    buf[rr * 65 + lane] = in[(r0 + rr) * C + c0 + lane];
  }
  __syncthreads();
  for (int pp = 0; pp < 16; ++pp) {
    int cc = pp * 4 + grp;
    out[(c0 + cc) * R + r0 + lane] = buf[lane * 65 + cc];
  }
}

// ---------------------------------------------------------------------------
// conv helpers for the fused encoder: load 27 x-taps, produce 4 channels.
// float2+float loads; fp32 math order identical to the original conv.
// ---------------------------------------------------------------------------
__device__ __forceinline__ void loadx27(const float* __restrict__ xb,
                                        float* xv) {
  #pragma unroll
  for (int c = 0; c < 3; ++c)
    #pragma unroll
    for (int ki = 0; ki < 3; ++ki) {
      const float* r = xb + c * 576 + ki * 24;
      float2 v01 = *(const float2*)r;
      float  v2  = r[2];
      xv[c * 9 + ki * 3 + 0] = v01.x;
      xv[c * 9 + ki * 3 + 1] = v01.y;
      xv[c * 9 + ki * 3 + 2] = v2;
    }
}
__device__ __forceinline__ void prod4(const float* __restrict__ wb,
                                      const float* xv, float* cvbase, int l) {
  #pragma unroll
  for (int q = 0; q < 4; ++q) {
    const float* wr = wb + q * 27;           // wave-uniform -> s_load
    float c0 = 0, c1 = 0, c2 = 0;
    #pragma unroll
    for (int m = 0; m < 27; m += 3) {
      c0 += xv[m] * wr[m]; c1 += xv[m+1] * wr[m+1]; c2 += xv[m+2] * wr[m+2];
    }
    cvbase[q * 68 + l] = (c0 + c1) + c2;     // stride 68: conflict-free reads
  }
}

// ---------------------------------------------------------------------------
// Encoder chain, 16 symmetric waves: 256 blocks x 1024 thr. EVERY wave does
// (a) one 16x16 chain MFMA tile (os = wv>>2, pq = wv&3) for step t and
// (b) the conv of 4 channels (wv*4..wv*4+3) for step t+1 -- so the per-step
// VALU load is balanced across all 16 waves (was: 8 producer waves at ~1000
// cyc/SIMD while 8 chain waves idled). CV stride 68 kills the 4-way bank
// conflict of the old stride-64 layout. Same barrier-parity safety: CV[t+1]
// written at step t, read at t+1, rewritten at t+2; Hs as verified.
// ---------------------------------------------------------------------------
__global__ __launch_bounds__(1024) void k_encmma(
    const float* __restrict__ x,
    const float* __restrict__ w0, const float* __restrict__ w0b,
    const float* __restrict__ r0, const float* __restrict__ r0b,
    unsigned short* __restrict__ st_out,   // 16 states x 1,048,576 bf16
    unsigned short* __restrict__ st_tail,  // 3 states
    float* __restrict__ h1f)
{
  __shared__ unsigned short Hs[2][4096];   // [p][c] bf16, XOR swizzle (16 KB)
  __shared__ float CV[2][4352];            // conv staging [c][p] stride 68
  int b = blockIdx.x, tid = threadIdx.x;
  int l = tid & 63;
  int wv = RL(tid >> 6);                   // 0..15

  // ---- chain tile setup: os = wv>>2 (o-strip), pq = wv&3 (p-quarter) ----
  int os = wv >> 2, pq = wv & 3;
  int co = os * 16 + (l >> 4) * 4;         // acc row base (o)
  int arow = os * 16 + (l & 15);           // A-frag row
  s16x8 avR[2];
  #pragma unroll
  for (int kk = 0; kk < 2; ++kk) {
    int cb = (kk * 4 + (l >> 4)) * 8;
    const float* src = r0 + arow * 64 + cb;
    #pragma unroll
    for (int j = 0; j < 8; ++j) avR[kk][j] = (short)f2bf(src[j]);
  }
  float b0v[4], b1v[4];
  #pragma unroll
  for (int r = 0; r < 4; ++r) {
    b0v[r] = w0b[co + r];
    b1v[r] = b0v[r] + r0b[co + r];
  }
  int p = pq * 16 + (l & 15);

  // ---- conv role setup: channels wv*4..wv*4+3, pixel l ----
  int ip = l >> 3, jp = l & 7;
  const float* xbase = x + ((size_t)b * 19 * 3) * 576 + (ip * 3) * 24 + jp * 3;
  const float* wb = w0 + wv * 4 * 27;      // wave-uniform
  float* cvrow0 = &CV[0][wv * 4 * 68];
  float* cvrow1 = &CV[1][wv * 4 * 68];

  float xv[27];
  loadx27(xbase, xv);                      // x[b][0]
  prod4(wb, xv, cvrow0, l);                // CV[0] = conv for t=0
  loadx27(xbase + (size_t)3 * 576, xv);    // prefetch x[b][1]
  __syncthreads();

  for (int t = 0; t <= 18; ++t) {
    // ---- chain part for step t ----
    f32x4 acc = (f32x4){0.f, 0.f, 0.f, 0.f};
    if (t > 0) {
      const unsigned short* cbuf = Hs[(t & 1) ^ 1];
      #pragma unroll
      for (int kk = 0; kk < 2; ++kk) {
        int chk = kk * 4 + (l >> 4);
        s16x8 bv = *(const s16x8*)&cbuf[p * 64 + ((chk ^ (p & 7)) << 3)];
        acc = __builtin_amdgcn_mfma_f32_16x16x32_bf16(avR[kk], bv, acc, 0, 0, 0);
      }
    }
    const float* cv = CV[t & 1];
    unsigned short* so = (t < 16)
        ? st_out  + (size_t)t * 1048576 + (size_t)b * 4096
        : st_tail + (size_t)(t - 16) * 1048576 + (size_t)b * 4096;
    unsigned short* nb = Hs[t & 1];
    {
      float v0 = relu_(acc[0] + cv[(co + 0) * 68 + p] + (t ? b1v[0] : b0v[0]));
      float v1 = relu_(acc[1] + cv[(co + 1) * 68 + p] + (t ? b1v[1] : b0v[1]));
      float v2 = relu_(acc[2] + cv[(co + 2) * 68 + p] + (t ? b1v[2] : b0v[2]));
      float v3 = relu_(acc[3] + cv[(co + 3) * 68 + p] + (t ? b1v[3] : b0v[3]));
      uint2 pk;
      pk.x = (unsigned)f2bf(v0) | ((unsigned)f2bf(v1) << 16);
      pk.y = (unsigned)f2bf(v2) | ((unsigned)f2bf(v3) << 16);
      *(uint2*)&nb[p * 64 + (((co >> 3) ^ (p & 7)) << 3) + (co & 7)] = pk;
      so[(co + 0) * 64 + p] = (unsigned short)(pk.x & 0xFFFF);
      so[(co + 1) * 64 + p] = (unsigned short)(pk.x >> 16);
      so[(co + 2) * 64 + p] = (unsigned short)(pk.y & 0xFFFF);
      so[(co + 3) * 64 + p] = (unsigned short)(pk.y >> 16);
      if (t == 18) {
        h1f[(size_t)b * 4096 + (co + 0) * 64 + p] = v0;
        h1f[(size_t)b * 4096 + (co + 1) * 64 + p] = v1;
        h1f[(size_t)b * 4096 + (co + 2) * 64 + p] = v2;
        h1f[(size_t)b * 4096 + (co + 3) * 64 + p] = v3;
      }
    }
    // ---- conv part for step t+1 ----
    if (t < 18) {
      prod4(wb, xv, (((t + 1) & 1) ? cvrow1 : cvrow0), l);
      if (t < 17)
        loadx27(xbase + (size_t)(t + 2) * 3 * 576, xv);     // prefetch t+2
    }
    __syncthreads();
  }
}

// ---------------------------------------------------------------------------
// MFMA contract, split-K x8: partsk[kts][t][b][o] = partial over K-slice kts.
// grid 19*16*8 = 2432 blocks (9.5/CU). BM=32, BN=128, BK=64, XOR swizzle.
// ---------------------------------------------------------------------------
__global__ __launch_bounds__(256) void k_conmma8(
    const unsigned short* __restrict__ st_out,
    const unsigned short* __restrict__ st_tail,
    const unsigned short* __restrict__ w1b,
    float* __restrict__ partsk)
{
  __shared__ unsigned short As[32 * 64];    // 4 KB
  __shared__ unsigned short Bs[128 * 64];   // 16 KB
  int bid = blockIdx.x, tid = threadIdx.x;
  int kts = bid & 7;
  int rem0 = bid >> 3;
  int t = rem0 >> 4, rem = rem0 & 15;
  int mt = rem >> 1, nt = rem & 1;
  int b0 = mt * 32, n0 = nt * 128;
  const unsigned short* abase = ((t < 16)
      ? st_out  + (size_t)t * 1048576
      : st_tail + (size_t)(t - 16) * 1048576) + (size_t)b0 * 4096;
  int w = RL(tid >> 6), l = tid & 63;
  int rh = w >> 1, chf = w & 1;

  int ar = tid >> 3, ac = tid & 7;
  unsigned short* adst = &As[ar * 64 + ((ac ^ (ar & 7)) << 3)];
  const unsigned short* asrc = abase + (size_t)ar * 4096 + (ac << 3);

  f32x4 acc[4];
  #pragma unroll
  for (int u = 0; u < 4; ++u) acc[u] = (f32x4){0.f, 0.f, 0.f, 0.f};

  for (int kt = 0; kt < 8; ++kt) {
    int k0 = kts * 512 + kt * 64;
    __syncthreads();                       // previous frag reads done
    *(s16x8*)adst = *(const s16x8*)(asrc + k0);
    #pragma unroll
    for (int cc = 0; cc < 4; ++cc) {
      int idx = cc * 256 + tid;
      int br = idx >> 3, bc = idx & 7;
      *(s16x8*)&Bs[br * 64 + ((bc ^ (br & 7)) << 3)] =
          *(const s16x8*)(w1b + (size_t)(n0 + br) * 4096 + k0 + (bc << 3));
    }
    __syncthreads();                       // tiles ready
    #pragma unroll
    for (int kk = 0; kk < 2; ++kk) {
      int arw = rh * 16 + (l & 15);
      int chk = kk * 4 + (l >> 4);
      s16x8 av = *(const s16x8*)&As[arw * 64 + ((chk ^ (arw & 7)) << 3)];
      #pragma unroll
      for (int u = 0; u < 4; ++u) {
        int brow = (chf * 4 + u) * 16 + (l & 15);
        s16x8 bv = *(const s16x8*)&Bs[brow * 64 + ((chk ^ (brow & 7)) << 3)];
        acc[u] = __builtin_amdgcn_mfma_f32_16x16x32_bf16(av, bv, acc[u], 0, 0, 0);
      }
    }
  }
  float* pb = partsk + (size_t)kts * 1245184 + (size_t)t * 65536;
  int colbase = n0 + chf * 64 + (l & 15);
  int rowbase = b0 + rh * 16 + (l >> 4) * 4;
  #pragma unroll
  for (int u = 0; u < 4; ++u)
    #pragma unroll
    for (int r = 0; r < 4; ++r)
      pb[(size_t)(rowbase + r) * 256 + colbase + u * 16] = acc[u][r];
}

// ---------------------------------------------------------------------------
// Fallback single-pass MFMA contract (used when workspace too small).
// ---------------------------------------------------------------------------
__global__ __launch_bounds__(256) void k_conmma(
    const unsigned short* __restrict__ st_out,
    const unsigned short* __restrict__ st_tail,
    const unsigned short* __restrict__ w1b,
    float* __restrict__ parts)
{
  __shared__ unsigned short As[32 * 64];    // 4 KB
  __shared__ unsigned short Bs[128 * 64];   // 16 KB
  int bid = blockIdx.x, tid = threadIdx.x;
  int t = bid >> 4, rem = bid & 15;
  int mt = rem >> 1, nt = rem & 1;
  int b0 = mt * 32, n0 = nt * 128;
  const unsigned short* abase = ((t < 16)
      ? st_out  + (size_t)t * 1048576
      : st_tail + (size_t)(t - 16) * 1048576) + (size_t)b0 * 4096;
  int w = RL(tid >> 6), l = tid & 63;
  int rh = w >> 1, chf = w & 1;

  int ar = tid >> 3, ac = tid & 7;
  unsigned short* adst = &As[ar * 64 + ((ac ^ (ar & 7)) << 3)];
  const unsigned short* asrc = abase + (size_t)ar * 4096 + (ac << 3);

  f32x4 acc[4];
  #pragma unroll
  for (int u = 0; u < 4; ++u) acc[u] = (f32x4){0.f, 0.f, 0.f, 0.f};

  for (int kt = 0; kt < 64; ++kt) {
    int k0 = kt * 64;
    __syncthreads();
    *(s16x8*)adst = *(const s16x8*)(asrc + k0);
    #pragma unroll
    for (int cc = 0; cc < 4; ++cc) {
      int idx = cc * 256 + tid;
      int br = idx >> 3, bc = idx & 7;
      *(s16x8*)&Bs[br * 64 + ((bc ^ (br & 7)) << 3)] =
          *(const s16x8*)(w1b + (size_t)(n0 + br) * 4096 + k0 + (bc << 3));
    }
    __syncthreads();
    #pragma unroll
    for (int kk = 0; kk < 2; ++kk) {
      int arw = rh * 16 + (l & 15);
      int chk = kk * 4 + (l >> 4);
      s16x8 av = *(const s16x8*)&As[arw * 64 + ((chk ^ (arw & 7)) << 3)];
      #pragma unroll
      for (int u = 0; u < 4; ++u) {
        int brow = (chf * 4 + u) * 16 + (l & 15);
        s16x8 bv = *(const s16x8*)&Bs[brow * 64 + ((chk ^ (brow & 7)) << 3)];
        acc[u] = __builtin_amdgcn_mfma_f32_16x16x32_bf16(av, bv, acc[u], 0, 0, 0);
      }
    }
  }
  float* pb = parts + (size_t)t * 65536;
  int colbase = n0 + chf * 64 + (l & 15);
  int rowbase = b0 + rh * 16 + (l >> 4) * 4;
  #pragma unroll
  for (int u = 0; u < 4; ++u)
    #pragma unroll
    for (int r = 0; r < 4; ++r)
      pb[(size_t)(rowbase + r) * 256 + colbase + u * 16] = acc[u][r];
}

// ---------------------------------------------------------------------------
// Full h2 pipeline: 256 blocks (1/batch) x 512 threads. FIRST pre-reduces the
// nslc split-K slices for THIS batch into LDS (parallel, coalesced, once).
// ---------------------------------------------------------------------------
__global__ __launch_bounds__(512, 1) void k_h2all(
    const float* __restrict__ partsk, int nslc,
    const float* __restrict__ w1b,
    const float* __restrict__ linT, const float* __restrict__ linb,
    const float* __restrict__ eps, float* __restrict__ scal,
    const float* __restrict__ dlinT, const float* __restrict__ dlinb,
    unsigned short* __restrict__ h2b)
{
  __shared__ float partsL[4864];             // 19 x 256 reduced h2h (19.4 KB)
  __shared__ float curL[256];
  __shared__ float ppart[512];
  __shared__ float red[256];
  int b = blockIdx.x, tid = threadIdx.x;
  const size_t SL = 1245184;
  // ---- one-shot parallel slice reduction for this batch ----
  for (int idx = tid; idx < 4864; idx += 512) {
    size_t off = (size_t)(idx >> 8) * 65536 + (size_t)b * 256 + (idx & 255);
    if (nslc == 8) {
      float s0 = partsk[off]          + partsk[SL + off];
      float s1 = partsk[2 * SL + off] + partsk[3 * SL + off];
      float s2 = partsk[4 * SL + off] + partsk[5 * SL + off];
      float s3 = partsk[6 * SL + off] + partsk[7 * SL + off];
      partsL[idx] = (s0 + s1) + (s2 + s3);
    } else {
      partsL[idx] = partsk[off];
    }
  }
  int o  = tid & 255, kh = tid >> 8;         // enc roles
  float wreg[128];
  #pragma unroll
  for (int jj = 0; jj < 128; ++jj)
    wreg[jj] = linT[(kh * 128 + jj) * 256 + o];
  __syncthreads();                           // partsL ready

  if (tid < 256)
    curL[tid] = relu_(partsL[tid] + w1b[tid]);
  __syncthreads();
  for (int t = 1; t <= 18; ++t) {
    float lacc = 0.f;
    #pragma unroll
    for (int jj = 0; jj < 128; ++jj)
      lacc += wreg[jj] * curL[kh * 128 + jj];   // LDS broadcast
    ppart[tid] = lacc;
    __syncthreads();                            // ppart ready; curL reads done
    if (tid < 256) {
      float h2h = relu_(partsL[t * 256 + tid] + w1b[tid]);
      curL[tid] = relu_(h2h + ppart[tid] + ppart[256 + tid] + linb[tid]);
    }
    __syncthreads();                            // curL ready for next step
  }
  if (tid < 128) {
    float mu = curL[tid], lv = curL[128 + tid];
    red[tid] = 0.5f * (expf(lv) + mu * mu - 1.0f - lv);
  }
  __syncthreads();
  for (int s = 64; s > 0; s >>= 1) {
    if (tid < s) red[tid] += red[tid + s];
    __syncthreads();
  }
  if (tid == 0) atomicAdd(&scal[1], red[0]);
  float hs = 0.f;
  if (tid < 128)
    hs = curL[tid] + expf(0.5f * curL[128 + tid]) * eps[(size_t)b * 128 + tid];
  __syncthreads();
  if (tid < 128) curL[tid] = hs;              // cur2 = h2s (128 entries)
  __syncthreads();

  int o2 = tid & 127, kh2 = (tid >> 7) & 1;
  float wreg2[64];
  if (tid < 256) {
    #pragma unroll
    for (int jj = 0; jj < 64; ++jj)
      wreg2[jj] = dlinT[(kh2 * 64 + jj) * 128 + o2];
  }
  for (int s = 0; s < 20; ++s) {
    if (tid < 256) {
      float lacc = 0.f;
      #pragma unroll
      for (int jj = 0; jj < 64; ++jj)
        lacc += wreg2[jj] * curL[kh2 * 64 + jj];
      ppart[tid] = lacc;
    }
    __syncthreads();                            // ppart ready; curL reads done
    if (tid < 128) {
      float v = relu_(ppart[tid] + ppart[128 + tid] + dlinb[tid]);
      h2b[(size_t)s * 32768 + (size_t)b * 128 + tid] = f2bf(v);
      curL[tid] = v;
    }
    __syncthreads();                            // curL ready for next step
  }
}

// ---------------------------------------------------------------------------
// VQ argmin quarters: grid 1024 (qtr = bid>>8, b = bid&255), from fp32 h1_18.
// ---------------------------------------------------------------------------
__global__ __launch_bounds__(256) void k_argmin(
    const float* __restrict__ h1f, const float* __restrict__ emb,
    const float* __restrict__ embsq,
    float* __restrict__ pbest, int* __restrict__ pidx)
{
  __shared__ float sd[256];
  __shared__ int   sk[256];
  int bid = blockIdx.x, tid = threadIdx.x;
  int qtr = bid >> 8, b = bid & 255;
  int p = tid & 63, kg = RL(tid >> 6);
  float f[64];
  const float* hb = h1f + (size_t)b * 4096 + p;
  #pragma unroll
  for (int c = 0; c < 64; ++c) f[c] = hb[c * 64];
  float best = 3.4e38f; int bk = 0;
  int kbeg = qtr * 128 + kg * 32;
  for (int k = kbeg; k < kbeg + 32; ++k) {
    const float* er = emb + k * 64;            // uniform -> s_load
    float d0 = 0, d1 = 0, d2 = 0, d3 = 0;
    #pragma unroll
    for (int c = 0; c < 64; c += 4) {
      d0 += f[c] * er[c];     d1 += f[c+1] * er[c+1];
      d2 += f[c+2] * er[c+2]; d3 += f[c+3] * er[c+3];
    }
    float d = embsq[k] - 2.f * ((d0 + d1) + (d2 + d3));
    if (d < best) { best = d; bk = k; }
  }
  sd[tid] = best; sk[tid] = bk;
  __syncthreads();
  if (tid < 64) {
    float bb = sd[tid]; int kk = sk[tid];
    #pragma unroll
    for (int g = 1; g < 4; ++g) {
      float dg = sd[g * 64 + tid];
      if (dg < bb) { bb = dg; kk = sk[g * 64 + tid]; }
    }
    pbest[qtr * 16384 + b * 64 + tid] = bb;
    pidx [qtr * 16384 + b * 64 + tid] = kk;
  }
}

// ---------------------------------------------------------------------------
// h1l placement: step d's projection, bf16.
// ---------------------------------------------------------------------------
__device__ __forceinline__ unsigned short* h1l_ptr(
    int d, int b, float* out, unsigned short* tail)
{
  if (d >= 1 && d <= 17)
    return (unsigned short*)(out + 2 + (size_t)b * 32832 + (size_t)(d - 1) * 1728);
  int slot = (d == 0) ? 0 : (d - 17);
  return tail + (size_t)slot * 1048576 + (size_t)b * 4096;
}

// ---------------------------------------------------------------------------
// MFMA h1l: h1l[d*256+b][n] = sum_j h2b[d*256+b][j] * dw1b[n][j], bf16 out.
// ---------------------------------------------------------------------------
__global__ __launch_bounds__(256) void k_declmma(
    const unsigned short* __restrict__ h2b,
    const unsigned short* __restrict__ dw1b,
    float* __restrict__ out, unsigned short* __restrict__ tail)
{
  __shared__ unsigned short As[64 * 128];   // 16 KB
  __shared__ unsigned short Bs[64 * 128];   // 16 KB
  int bid = blockIdx.x, tid = threadIdx.x;
  int mt = bid >> 6, nt = bid & 63;
  int m0 = mt * 64, n0 = nt * 64;
  int w = RL(tid >> 6), l = tid & 63;

  #pragma unroll
  for (int cc = 0; cc < 4; ++cc) {
    int idx = cc * 256 + tid;
    int row = idx >> 4, col = idx & 15;
    *(s16x8*)&As[row * 128 + ((col ^ (row & 7)) << 3)] =
        *(const s16x8*)(h2b + (size_t)(m0 + row) * 128 + (col << 3));
    *(s16x8*)&Bs[row * 128 + ((col ^ (row & 7)) << 3)] =
        *(const s16x8*)(dw1b + (size_t)(n0 + row) * 128 + (col << 3));
  }
  __syncthreads();

  f32x4 acc[4];
  #pragma unroll
  for (int u = 0; u < 4; ++u) acc[u] = (f32x4){0.f, 0.f, 0.f, 0.f};
  int arow = w * 16 + (l & 15);
  #pragma unroll
  for (int kk = 0; kk < 4; ++kk) {
    int chk = kk * 4 + (l >> 4);
    s16x8 av = *(const s16x8*)&As[arow * 128 + ((chk ^ (arow & 7)) << 3)];
    #pragma unroll
    for (int u = 0; u < 4; ++u) {
      int brow = u * 16 + (l & 15);
      s16x8 bv = *(const s16x8*)&Bs[brow * 128 + ((chk ^ (brow & 7)) << 3)];
      acc[u] = __builtin_amdgcn_mfma_f32_16x16x32_bf16(av, bv, acc[u], 0, 0, 0);
    }
  }
  int d = m0 >> 8;                        // uniform per block
  #pragma unroll
  for (int r = 0; r < 4; ++r) {
    int b = (m0 & 255) + w * 16 + (l >> 4) * 4 + r;
    unsigned short* op = h1l_ptr(d, b, out, tail);
    #pragma unroll
    for (int u = 0; u < 4; ++u)
      op[n0 + u * 16 + (l & 15)] = f2bf(acc[u][r]);
  }
}

// ---------------------------------------------------------------------------
// VQ stats: grid 256 (one batch): merge quarters, Q, loss, histogram.
// ---------------------------------------------------------------------------
__global__ __launch_bounds__(256) void k_vqstats(
    const float* __restrict__ h1f, const float* __restrict__ emb,
    const float* __restrict__ pbest, const int* __restrict__ pidx,
    float* __restrict__ Q, float* __restrict__ counts,
    float* __restrict__ loss_sum)
{
  __shared__ int   fk[64];
  __shared__ int   lhist[512];
  __shared__ float red[256];
  int b = blockIdx.x, tid = threadIdx.x;
  for (int j = tid; j < 512; j += 256) lhist[j] = 0;
  __syncthreads();
  if (tid < 64) {
    float bb = pbest[b * 64 + tid];
    int   kk = pidx [b * 64 + tid];
    #pragma unroll
    for (int q = 1; q < 4; ++q) {
      float dq = pbest[q * 16384 + b * 64 + tid];
      if (dq < bb) { bb = dq; kk = pidx[q * 16384 + b * 64 + tid]; }
    }
    fk[tid] = kk;
    atomicAdd(&lhist[kk], 1);
  }
  __syncthreads();
  int p = tid & 63, cgi = tid >> 6;
  int kk = fk[p];
  const float* eb = emb + kk * 64 + cgi * 16;
  const float* hz = h1f + (size_t)b * 4096 + cgi * 1024 + p;
  float* qb = Q + (size_t)b * 4096 + cgi * 1024 + p;
  float ls = 0;
  #pragma unroll
  for (int c = 0; c < 16; ++c) {
    float e = eb[c];
    float z = hz[c * 64];
    float dd = e - z;
    ls += dd * dd;
    qb[c * 64] = e;
  }
  red[tid] = ls;
  __syncthreads();
  for (int s = 128; s > 0; s >>= 1) { if (tid < s) red[tid] += red[tid + s]; __syncthreads(); }
  if (tid == 0) atomicAdd(loss_sum, red[0]);
  for (int j = tid; j < 512; j += 256) {
    int h = lhist[j];
    if (h > 0) atomicAdd(&counts[j], (float)h);
  }
}

// ---------------------------------------------------------------------------
// Decoder chain, MFMA edition. 256 blocks (one batch) x 1024 thr = 16 waves:
//  waves 0..7  : state update Hnew = relu(dr0 . H + h1l + bias) via MFMA
//  waves 8..15 : frame emit y = w0d^T . H via MFMA, one iteration behind
// Block 256 finalizes scalars.
// ---------------------------------------------------------------------------
__global__ __launch_bounds__(1024) void k_decchain(
    const float* __restrict__ Q,
    const float* __restrict__ dr0, const float* __restrict__ dr0b,
    const float* __restrict__ dw1b_bias,
    const float* __restrict__ w0d, const float* __restrict__ w0db,
    float* __restrict__ out, unsigned short* __restrict__ tail,
    const float* __restrict__ counts, const float* __restrict__ scal)
{
  int bid = blockIdx.x, tid = threadIdx.x;
  if (bid == 256) {            // ---- finalize ----
    __shared__ float red[512];
    if (tid < 512) {
      float avg = counts[tid] * (1.0f / 16384.0f);
      red[tid] = avg * logf(avg + 1e-10f);
    }
    __syncthreads();
    for (int s = 256; s > 0; s >>= 1) {
      if (tid < s) red[tid] += red[tid + s];
      __syncthreads();
    }
    if (tid == 0) {
      out[0] = 0.25f * scal[0] * (1.0f / 1048576.0f);
      out[1] = scal[1] * (1.0f / 256.0f);
      out[2 + 8404992] = expf(-red[0]);
    }
    return;
  }
  __shared__ unsigned short Hs[2][4096];   // [p][c] bf16, 16B-chunk XOR swizzle
  int b = bid;
  int l = tid & 63;
  int wv = RL(tid >> 6);

  for (int idx = tid; idx < 4096; idx += 1024) {
    int c = idx >> 6, p = idx & 63;
    Hs[0][p * 64 + ((((c >> 3) ^ (p & 7))) << 3) + (c & 7)] =
        f2bf(Q[(size_t)b * 4096 + idx]);
  }

  if (wv < 8) {
    // ---------------- update waves ----------------
    int os = wv >> 1;                    // o-strip 0..3
    int ph = wv & 1;                     // p-half 0..1
    int co = os * 16 + (l >> 4) * 4;     // acc row base (o)
    int arow = os * 16 + (l & 15);       // A-frag row
    s16x8 avR[2];
    #pragma unroll
    for (int kk = 0; kk < 2; ++kk) {
      int cb = (kk * 4 + (l >> 4)) * 8;
      const float* src = dr0 + arow * 64 + cb;
      #pragma unroll
      for (int j = 0; j < 8; ++j) avR[kk][j] = (short)f2bf(src[j]);
    }
    float biasv[4];
    #pragma unroll
    for (int r = 0; r < 4; ++r) biasv[r] = dr0b[co + r] + dw1b_bias[co + r];
    int pA = (ph * 2) * 16 + (l & 15);
    int pB = (ph * 2 + 1) * 16 + (l & 15);
    __syncthreads();

    for (int i = 0; i <= 20; ++i) {
      if (i <= 19) {
        const unsigned short* lp = h1l_ptr(i, b, out, tail);
        float hlA[4], hlB[4];
        #pragma unroll
        for (int r = 0; r < 4; ++r) {
          hlA[r] = bf2f(lp[(co + r) * 64 + pA]);
          hlB[r] = bf2f(lp[(co + r) * 64 + pB]);
        }
        const unsigned short* cb = Hs[i & 1];
        f32x4 accA = (f32x4){0.f, 0.f, 0.f, 0.f};
        f32x4 accB = (f32x4){0.f, 0.f, 0.f, 0.f};
        #pragma unroll
        for (int kk = 0; kk < 2; ++kk) {
          int chk = kk * 4 + (l >> 4);
          s16x8 bvA = *(const s16x8*)&cb[pA * 64 + ((chk ^ (pA & 7)) << 3)];
          s16x8 bvB = *(const s16x8*)&cb[pB * 64 + ((chk ^ (pB & 7)) << 3)];
          accA = __builtin_amdgcn_mfma_f32_16x16x32_bf16(avR[kk], bvA, accA, 0, 0, 0);
          accB = __builtin_amdgcn_mfma_f32_16x16x32_bf16(avR[kk], bvB, accB, 0, 0, 0);
        }
        unsigned short* nb = Hs[(i + 1) & 1];
        {
          float v0 = relu_(accA[0] + hlA[0] + biasv[0]);
          float v1 = relu_(accA[1] + hlA[1] + biasv[1]);
          float v2 = relu_(accA[2] + hlA[2] + biasv[2]);
          float v3 = relu_(accA[3] + hlA[3] + biasv[3]);
          uint2 pk;
          pk.x = (unsigned)f2bf(v0) | ((unsigned)f2bf(v1) << 16);
          pk.y = (unsigned)f2bf(v2) | ((unsigned)f2bf(v3) << 16);
          *(uint2*)&nb[pA * 64 + (((co >> 3) ^ (pA & 7)) << 3) + (co & 7)] = pk;
        }
        {
          float v0 = relu_(accB[0] + hlB[0] + biasv[0]);
          float v1 = relu_(accB[1] + hlB[1] + biasv[1]);
          float v2 = relu_(accB[2] + hlB[2] + biasv[2]);
          float v3 = relu_(accB[3] + hlB[3] + biasv[3]);
          uint2 pk;
          pk.x = (unsigned)f2bf(v0) | ((unsigned)f2bf(v1) << 16);
          pk.y = (unsigned)f2bf(v2) | ((unsigned)f2bf(v3) << 16);
          *(uint2*)&nb[pB * 64 + (((co >> 3) ^ (pB & 7)) << 3) + (co & 7)] = pk;
        }
      }
      __syncthreads();
    }
  } else {
    // ---------------- emit waves ----------------
    int job = wv - 8;
    int mt = job >> 2, pt = job & 3;
    int m0 = mt * 16 + (l >> 4) * 4;     // acc row base (m)
    int am = mt * 16 + (l & 15);         // A-frag row
    s16x8 avE[2];
    #pragma unroll
    for (int kk = 0; kk < 2; ++kk) {
      int cbg = (kk * 4 + (l >> 4)) * 8;
      #pragma unroll
      for (int j = 0; j < 8; ++j)
        avE[kk][j] = (am < 27) ? (short)f2bf(w0d[(cbg + j) * 27 + am]) : (short)0;
    }
    int p = pt * 16 + (l & 15);
    int hrow = p >> 3, wcol = p & 7;
    int preoff[4]; float eb[4]; bool vld[4];
    #pragma unroll
    for (int r = 0; r < 4; ++r) {
      int m = m0 + r;
      vld[r] = (m < 27);
      int mm = vld[r] ? m : 0;
      int o3 = mm / 9, rr = mm % 9, ki = rr / 3, kj = rr % 3;
      preoff[r] = o3 * 576 + (hrow * 3 + ki) * 24 + wcol * 3 + kj;
      eb[r] = w0db[o3];
    }
    __syncthreads();

    for (int i = 0; i <= 20; ++i) {
      if (i >= 2) {
        const unsigned short* cb = Hs[i & 1];
        f32x4 acc = (f32x4){0.f, 0.f, 0.f, 0.f};
        #pragma unroll
        for (int kk = 0; kk < 2; ++kk) {
          int chk = kk * 4 + (l >> 4);
          s16x8 bv = *(const s16x8*)&cb[p * 64 + ((chk ^ (p & 7)) << 3)];
          acc = __builtin_amdgcn_mfma_f32_16x16x32_bf16(avE[kk], bv, acc, 0, 0, 0);
        }
        int t = i - 2;
        float* fb = out + 2 + (size_t)(b * 19 + t) * 1728;
        #pragma unroll
        for (int r = 0; r < 4; ++r) {
          if (vld[r]) {
            float v = acc[r] + eb[r];
            v = v > 0.f ? v : expm1f(v);             // ELU alpha=1
            fb[preoff[r]] = v;
          }
        }
      }
      __syncthreads();
    }
  }
}

// ---------------------------------------------------------------------------
extern "C" void kernel_launch(void* const* d_in, const int* in_sizes, int n_in,
                              void* d_out, int out_size, void* d_ws, size_t ws_size,
                              hipStream_t stream)
{
  const float* x     = (const float*)d_in[0];
  const float* eps   = (const float*)d_in[1];
  const float* emb   = (const float*)d_in[2];
  const float* ew0   = (const float*)d_in[3];
  const float* ew0b  = (const float*)d_in[4];
  const float* ew1   = (const float*)d_in[5];
  const float* ew1b  = (const float*)d_in[6];
  const float* er0   = (const float*)d_in[7];
  const float* er0b  = (const float*)d_in[8];
  const float* elinw = (const float*)d_in[9];
  const float* elinb = (const float*)d_in[10];
  const float* dw0   = (const float*)d_in[11];
  const float* dw0b  = (const float*)d_in[12];
  const float* dw1   = (const float*)d_in[13];
  const float* dw1b  = (const float*)d_in[14];
  const float* dr0   = (const float*)d_in[15];
  const float* dr0b  = (const float*)d_in[16];
  const float* dlinw = (const float*)d_in[17];
  const float* dlinb = (const float*)d_in[18];
  float* out = (float*)d_out;
  float* ws  = (float*)d_ws;

  // ws layout (floats): base ~22.6 MB; split-K partials (40 MB) appended.
  unsigned short* W1B = (unsigned short*)ws;  // 256x4096 bf16; Q overlays
  float* Q      = ws + 0;          // 256x4096 fp32
  float* LINT   = ws + 1048576;    // 256x256 (j-major)
  float* DLINT  = ws + 1114112;    // 128x128 (j-major)
  float* EMBSQ  = ws + 1130496;    // 512
  float* H1F    = ws + 1131008;    // 256x4096 fp32 h1_18
  float* PARTS  = ws + 2179584;    // 19x256x256 (fallback contract output)
  float* PBEST  = ws + 2179584;    // overlays PARTS (argmin after h2all)
  int*   PIDX   = (int*)(ws + 2245120);
  unsigned short* TAIL = (unsigned short*)(ws + 3424768); // 3x1,048,576 bf16
  unsigned short* H2B  = (unsigned short*)(ws + 4997632); // 5120x128 bf16
  unsigned short* DW1B = (unsigned short*)(ws + 5325312); // 4096x128 bf16
  float* SCAL   = ws + 5652992;    // [0]=loss, [1]=kl
  float* COUNTS = ws + 5652994;    // 512
  const size_t XC_OFF = 5653508;   // 16B-aligned; split-K partial region
  const size_t XC_END = XC_OFF + (size_t)8 * 1245184;  // 8 slices, ~40 MB
  bool big = ws_size >= XC_END * sizeof(float);
  float* PARTSK = big ? (ws + XC_OFF) : nullptr;

  unsigned short* ST_OUT = (unsigned short*)(out + 2);  // 16 bf16 h1 states

  k_prep<<<213, 256, 0, stream>>>(ew1, elinw, dlinw, emb, dw1, W1B, LINT,
                                  DLINT, EMBSQ, DW1B, SCAL, COUNTS);
  k_encmma<<<256, 1024, 0, stream>>>(x, ew0, ew0b, er0, er0b,
                                     ST_OUT, TAIL, H1F);
  const float* parts_src;
  int nslc;
  if (big) {
    k_conmma8<<<2432, 256, 0, stream>>>(ST_OUT, TAIL, W1B, PARTSK);
    parts_src = PARTSK; nslc = 8;
  } else {
    k_conmma<<<304, 256, 0, stream>>>(ST_OUT, TAIL, W1B, PARTS);
    parts_src = PARTS; nslc = 1;
  }
  k_h2all<<<256, 512, 0, stream>>>(parts_src, nslc, ew1b, LINT, elinb, eps,
                                   SCAL, DLINT, dlinb, H2B);
  k_argmin<<<1024, 256, 0, stream>>>(H1F, emb, EMBSQ, PBEST, PIDX);
  k_declmma<<<5120, 256, 0, stream>>>(H2B, DW1B, out, TAIL);
  k_vqstats<<<256, 256, 0, stream>>>(H1F, emb, PBEST, PIDX, Q, COUNTS,
                                     &SCAL[0]);
  k_decchain<<<257, 1024, 0, stream>>>(Q, dr0, dr0b, dw1b, dw0, dw0b,
                                       out, TAIL, COUNTS, SCAL);
}

// Round 13
// 294.072 us; speedup vs baseline: 1.0488x; 1.0488x over previous
//
#include <hip/hip_runtime.h>
#include <math.h>

#define RL(x) __builtin_amdgcn_readfirstlane(x)

typedef short  s16x8 __attribute__((ext_vector_type(8)));
typedef float  f32x4 __attribute__((ext_vector_type(4)));

__device__ __forceinline__ float relu_(float v) { return v > 0.f ? v : 0.f; }
__device__ __forceinline__ unsigned short f2bf(float f) {
  unsigned u = __float_as_uint(f);
  u += 0x7FFFu + ((u >> 16) & 1u);           // round-to-nearest-even
  return (unsigned short)(u >> 16);
}
__device__ __forceinline__ float bf2f(unsigned short h) {
  return __uint_as_float((unsigned)h << 16);
}

// ---------------------------------------------------------------------------
// Prep: w1 -> bf16 copy, dw1 -> bf16 transpose [n][k], LINT/DLINT transposes,
// |emb|^2, zero SCAL/COUNTS. grid 213.
// ---------------------------------------------------------------------------
__global__ __launch_bounds__(256) void k_prep(
    const float* __restrict__ w1, const float* __restrict__ linw,
    const float* __restrict__ dlinw, const float* __restrict__ emb,
    const float* __restrict__ dw1,
    unsigned short* __restrict__ w1b, float* __restrict__ linT,
    float* __restrict__ dlinT, float* __restrict__ embsq,
    unsigned short* __restrict__ dw1b,
    float* __restrict__ scal, float* __restrict__ counts)
{
  int bid = blockIdx.x, tid = threadIdx.x;
  if (bid < 64) {                      // ---- w1 -> bf16 (no transpose) ----
    #pragma unroll
    for (int j = 0; j < 32; ++j) {
      int idx = bid * 16384 + j * 512 + tid * 2;
      float2 v = *(const float2*)(w1 + idx);
      unsigned pk = ((unsigned)f2bf(v.y) << 16) | (unsigned)f2bf(v.x);
      *(unsigned*)&w1b[idx] = pk;
    }
    return;
  }
  if (bid == 84) {
    if (tid < 2) scal[tid] = 0.f;
    for (int j = tid; j < 512; j += 256) counts[j] = 0.f;
    return;
  }
  if (bid >= 85) {                     // ---- dw1 transpose -> bf16 ----
    __shared__ float tbuf[64 * 65];
    int idx = bid - 85;
    int r0 = (idx >> 6) * 64, c0 = (idx & 63) * 64;
    int lane = tid & 63, grp = tid >> 6;
    for (int pp = 0; pp < 16; ++pp) {
      int rr = pp * 4 + grp;
      tbuf[rr * 65 + lane] = dw1[(size_t)(r0 + rr) * 4096 + c0 + lane];
    }
    __syncthreads();
    for (int pp = 0; pp < 16; ++pp) {
      int cc = pp * 4 + grp;
      dw1b[(size_t)(c0 + cc) * 128 + r0 + lane] = f2bf(tbuf[lane * 65 + cc]);
    }
    return;
  }
  if (bid >= 82) {
    int k = (bid - 82) * 256 + tid;
    const float* e = emb + k * 64;
    float s0 = 0, s1 = 0, s2 = 0, s3 = 0;
    #pragma unroll
    for (int c = 0; c < 64; c += 4) {
      s0 += e[c] * e[c]; s1 += e[c+1] * e[c+1];
      s2 += e[c+2] * e[c+2]; s3 += e[c+3] * e[c+3];
    }
    embsq[k] = (s0 + s1) + (s2 + s3);
    return;
  }
  __shared__ float buf[64 * 65];
  const float* in; float* out; int R, C, tr, tc;
  if (bid < 80) { in = linw;  out = linT;  R = 256; C = 256; tr = (bid - 64) >> 2; tc = (bid - 64) & 3; }
  else          { in = dlinw; out = dlinT; R = 128; C = 128; tr = (bid - 80) >> 1; tc = (bid - 80) & 1; }
  int r0 = tr * 64, c0 = tc * 64;
  int lane = tid & 63, grp = tid >> 6;
  for (int pp = 0; pp < 16; ++pp) {
    int rr = pp * 4 + grp;
    buf[rr * 65 + lane] = in[(r0 + rr) * C + c0 + lane];
  }
  __syncthreads();
  for (int pp = 0; pp < 16; ++pp) {
    int cc = pp * 4 + grp;
    out[(c0 + cc) * R + r0 + lane] = buf[lane * 65 + cc];
  }
}

// ---------------------------------------------------------------------------
// conv helpers for the fused encoder: load 27 x-taps, produce 8 channels.
// float2+float loads (same addresses, same fp32 order -> bit-identical).
// ---------------------------------------------------------------------------
__device__ __forceinline__ void loadx27(const float* __restrict__ xb,
                                        float* xv) {
  #pragma unroll
  for (int c = 0; c < 3; ++c)
    #pragma unroll
    for (int ki = 0; ki < 3; ++ki) {
      const float* r = xb + c * 576 + ki * 24;
      float2 v01 = *(const float2*)r;
      float  v2  = r[2];
      xv[c * 9 + ki * 3 + 0] = v01.x;
      xv[c * 9 + ki * 3 + 1] = v01.y;
      xv[c * 9 + ki * 3 + 2] = v2;
    }
}
__device__ __forceinline__ void prod8(const float* __restrict__ wb,
                                      const float* xv, float* cvrow, int l) {
  #pragma unroll
  for (int q = 0; q < 8; ++q) {
    const float* wr = wb + q * 27;           // wave-uniform -> s_load
    float c0 = 0, c1 = 0, c2 = 0;
    #pragma unroll
    for (int m = 0; m < 27; m += 3) {
      c0 += xv[m] * wr[m]; c1 += xv[m+1] * wr[m+1]; c2 += xv[m+2] * wr[m+2];
    }
    cvrow[q * 64 + l] = (c0 + c1) + c2;
  }
}

// ---------------------------------------------------------------------------
// Encoder chain, MFMA + producer-wave conv: 256 blocks x 1024 thr = 16 waves.
//  waves 0..7  : MFMA chain Hnew = relu(CV[t] + r0.H + bias)  [setprio(1)
//                around the latency-critical chain phase -- T5: role-split]
//  waves 8..15 : conv producers -- step t+1's conv into CV[(t+1)&1],
//                concurrent with the chain's step t. One barrier/step.
// (Round-11-measured structure: 41 us. Round-12's symmetric rebalance
//  regressed to 58 us -- reverted.)
// ---------------------------------------------------------------------------
__global__ __launch_bounds__(1024) void k_encmma(
    const float* __restrict__ x,
    const float* __restrict__ w0, const float* __restrict__ w0b,
    const float* __restrict__ r0, const float* __restrict__ r0b,
    unsigned short* __restrict__ st_out,   // 16 states x 1,048,576 bf16
    unsigned short* __restrict__ st_tail,  // 3 states
    float* __restrict__ h1f)
{
  __shared__ unsigned short Hs[2][4096];   // [p][c] bf16, XOR swizzle (16 KB)
  __shared__ float CV[2][4096];            // conv staging [c][p] (32 KB)
  int b = blockIdx.x, tid = threadIdx.x;
  int l = tid & 63;
  int wv = RL(tid >> 6);                   // 0..15

  if (wv >= 8) {
    // ---------------- conv producer waves ----------------
    int pw = wv - 8;                       // 0..7: channels pw*8..pw*8+7
    int ip = l >> 3, jp = l & 7;
    const float* xbase = x + ((size_t)b * 19 * 3) * 576 + (ip * 3) * 24 + jp * 3;
    const float* wb = w0 + pw * 8 * 27;    // wave-uniform
    float* cvrow0 = &CV[0][pw * 8 * 64];
    float* cvrow1 = &CV[1][pw * 8 * 64];

    float xv[27];
    loadx27(xbase, xv);                    // x[b][0]
    prod8(wb, xv, cvrow0, l);              // CV[0] = conv for t=0
    loadx27(xbase + (size_t)3 * 576, xv);  // prefetch x[b][1]
    __syncthreads();

    for (int t = 0; t <= 18; ++t) {
      if (t < 18) {
        prod8(wb, xv, (((t + 1) & 1) ? cvrow1 : cvrow0), l);  // conv t+1
        if (t < 17)
          loadx27(xbase + (size_t)(t + 2) * 3 * 576, xv);     // prefetch t+2
      }
      __syncthreads();
    }
    return;
  }

  // ---------------- chain waves ----------------
  int os = wv >> 1, ph = wv & 1;
  int co = os * 16 + (l >> 4) * 4;         // acc row base (o)
  int arow = os * 16 + (l & 15);           // A-frag row
  s16x8 avR[2];
  #pragma unroll
  for (int kk = 0; kk < 2; ++kk) {
    int cb = (kk * 4 + (l >> 4)) * 8;
    const float* src = r0 + arow * 64 + cb;
    #pragma unroll
    for (int j = 0; j < 8; ++j) avR[kk][j] = (short)f2bf(src[j]);
  }
  float b0v[4], b1v[4];
  #pragma unroll
  for (int r = 0; r < 4; ++r) {
    b0v[r] = w0b[co + r];
    b1v[r] = b0v[r] + r0b[co + r];
  }
  int pA = ph * 32 + (l & 15);
  int pB = pA + 16;
  __syncthreads();                         // CV[0] ready

  for (int t = 0; t <= 18; ++t) {
    __builtin_amdgcn_s_setprio(1);         // favor chain waves vs producers
    f32x4 accA = (f32x4){0.f, 0.f, 0.f, 0.f};
    f32x4 accB = (f32x4){0.f, 0.f, 0.f, 0.f};
    if (t > 0) {
      const unsigned short* cbuf = Hs[(t & 1) ^ 1];
      #pragma unroll
      for (int kk = 0; kk < 2; ++kk) {
        int chk = kk * 4 + (l >> 4);
        s16x8 bvA = *(const s16x8*)&cbuf[pA * 64 + ((chk ^ (pA & 7)) << 3)];
        s16x8 bvB = *(const s16x8*)&cbuf[pB * 64 + ((chk ^ (pB & 7)) << 3)];
        accA = __builtin_amdgcn_mfma_f32_16x16x32_bf16(avR[kk], bvA, accA, 0, 0, 0);
        accB = __builtin_amdgcn_mfma_f32_16x16x32_bf16(avR[kk], bvB, accB, 0, 0, 0);
      }
    }
    const float* cv = CV[t & 1];
    unsigned short* so = (t < 16)
        ? st_out  + (size_t)t * 1048576 + (size_t)b * 4096
        : st_tail + (size_t)(t - 16) * 1048576 + (size_t)b * 4096;
    unsigned short* nb = Hs[t & 1];
    {
      float v0 = relu_(accA[0] + cv[(co + 0) * 64 + pA] + (t ? b1v[0] : b0v[0]));
      float v1 = relu_(accA[1] + cv[(co + 1) * 64 + pA] + (t ? b1v[1] : b0v[1]));
      float v2 = relu_(accA[2] + cv[(co + 2) * 64 + pA] + (t ? b1v[2] : b0v[2]));
      float v3 = relu_(accA[3] + cv[(co + 3) * 64 + pA] + (t ? b1v[3] : b0v[3]));
      uint2 pk;
      pk.x = (unsigned)f2bf(v0) | ((unsigned)f2bf(v1) << 16);
      pk.y = (unsigned)f2bf(v2) | ((unsigned)f2bf(v3) << 16);
      *(uint2*)&nb[pA * 64 + (((co >> 3) ^ (pA & 7)) << 3) + (co & 7)] = pk;
      so[(co + 0) * 64 + pA] = (unsigned short)(pk.x & 0xFFFF);
      so[(co + 1) * 64 + pA] = (unsigned short)(pk.x >> 16);
      so[(co + 2) * 64 + pA] = (unsigned short)(pk.y & 0xFFFF);
      so[(co + 3) * 64 + pA] = (unsigned short)(pk.y >> 16);
      if (t == 18) {
        h1f[(size_t)b * 4096 + (co + 0) * 64 + pA] = v0;
        h1f[(size_t)b * 4096 + (co + 1) * 64 + pA] = v1;
        h1f[(size_t)b * 4096 + (co + 2) * 64 + pA] = v2;
        h1f[(size_t)b * 4096 + (co + 3) * 64 + pA] = v3;
      }
    }
    {
      float v0 = relu_(accB[0] + cv[(co + 0) * 64 + pB] + (t ? b1v[0] : b0v[0]));
      float v1 = relu_(accB[1] + cv[(co + 1) * 64 + pB] + (t ? b1v[1] : b0v[1]));
      float v2 = relu_(accB[2] + cv[(co + 2) * 64 + pB] + (t ? b1v[2] : b0v[2]));
      float v3 = relu_(accB[3] + cv[(co + 3) * 64 + pB] + (t ? b1v[3] : b0v[3]));
      uint2 pk;
      pk.x = (unsigned)f2bf(v0) | ((unsigned)f2bf(v1) << 16);
      pk.y = (unsigned)f2bf(v2) | ((unsigned)f2bf(v3) << 16);
      *(uint2*)&nb[pB * 64 + (((co >> 3) ^ (pB & 7)) << 3) + (co & 7)] = pk;
      so[(co + 0) * 64 + pB] = (unsigned short)(pk.x & 0xFFFF);
      so[(co + 1) * 64 + pB] = (unsigned short)(pk.x >> 16);
      so[(co + 2) * 64 + pB] = (unsigned short)(pk.y & 0xFFFF);
      so[(co + 3) * 64 + pB] = (unsigned short)(pk.y >> 16);
      if (t == 18) {
        h1f[(size_t)b * 4096 + (co + 0) * 64 + pB] = v0;
        h1f[(size_t)b * 4096 + (co + 1) * 64 + pB] = v1;
        h1f[(size_t)b * 4096 + (co + 2) * 64 + pB] = v2;
        h1f[(size_t)b * 4096 + (co + 3) * 64 + pB] = v3;
      }
    }
    __builtin_amdgcn_s_setprio(0);
    __syncthreads();
  }
}

// ---------------------------------------------------------------------------
// MFMA contract, split-K x8: partsk[kts][t][b][o] = partial over K-slice kts.
// grid 19*16*8 = 2432 blocks (9.5/CU). BM=32, BN=128, BK=64, XOR swizzle.
// ---------------------------------------------------------------------------
__global__ __launch_bounds__(256) void k_conmma8(
    const unsigned short* __restrict__ st_out,
    const unsigned short* __restrict__ st_tail,
    const unsigned short* __restrict__ w1b,
    float* __restrict__ partsk)
{
  __shared__ unsigned short As[32 * 64];    // 4 KB
  __shared__ unsigned short Bs[128 * 64];   // 16 KB
  int bid = blockIdx.x, tid = threadIdx.x;
  int kts = bid & 7;
  int rem0 = bid >> 3;
  int t = rem0 >> 4, rem = rem0 & 15;
  int mt = rem >> 1, nt = rem & 1;
  int b0 = mt * 32, n0 = nt * 128;
  const unsigned short* abase = ((t < 16)
      ? st_out  + (size_t)t * 1048576
      : st_tail + (size_t)(t - 16) * 1048576) + (size_t)b0 * 4096;
  int w = RL(tid >> 6), l = tid & 63;
  int rh = w >> 1, chf = w & 1;

  int ar = tid >> 3, ac = tid & 7;
  unsigned short* adst = &As[ar * 64 + ((ac ^ (ar & 7)) << 3)];
  const unsigned short* asrc = abase + (size_t)ar * 4096 + (ac << 3);

  f32x4 acc[4];
  #pragma unroll
  for (int u = 0; u < 4; ++u) acc[u] = (f32x4){0.f, 0.f, 0.f, 0.f};

  for (int kt = 0; kt < 8; ++kt) {
    int k0 = kts * 512 + kt * 64;
    __syncthreads();                       // previous frag reads done
    *(s16x8*)adst = *(const s16x8*)(asrc + k0);
    #pragma unroll
    for (int cc = 0; cc < 4; ++cc) {
      int idx = cc * 256 + tid;
      int br = idx >> 3, bc = idx & 7;
      *(s16x8*)&Bs[br * 64 + ((bc ^ (br & 7)) << 3)] =
          *(const s16x8*)(w1b + (size_t)(n0 + br) * 4096 + k0 + (bc << 3));
    }
    __syncthreads();                       // tiles ready
    #pragma unroll
    for (int kk = 0; kk < 2; ++kk) {
      int arw = rh * 16 + (l & 15);
      int chk = kk * 4 + (l >> 4);
      s16x8 av = *(const s16x8*)&As[arw * 64 + ((chk ^ (arw & 7)) << 3)];
      #pragma unroll
      for (int u = 0; u < 4; ++u) {
        int brow = (chf * 4 + u) * 16 + (l & 15);
        s16x8 bv = *(const s16x8*)&Bs[brow * 64 + ((chk ^ (brow & 7)) << 3)];
        acc[u] = __builtin_amdgcn_mfma_f32_16x16x32_bf16(av, bv, acc[u], 0, 0, 0);
      }
    }
  }
  float* pb = partsk + (size_t)kts * 1245184 + (size_t)t * 65536;
  int colbase = n0 + chf * 64 + (l & 15);
  int rowbase = b0 + rh * 16 + (l >> 4) * 4;
  #pragma unroll
  for (int u = 0; u < 4; ++u)
    #pragma unroll
    for (int r = 0; r < 4; ++r)
      pb[(size_t)(rowbase + r) * 256 + colbase + u * 16] = acc[u][r];
}

// ---------------------------------------------------------------------------
// Fallback single-pass MFMA contract (used when workspace too small).
// ---------------------------------------------------------------------------
__global__ __launch_bounds__(256) void k_conmma(
    const unsigned short* __restrict__ st_out,
    const unsigned short* __restrict__ st_tail,
    const unsigned short* __restrict__ w1b,
    float* __restrict__ parts)
{
  __shared__ unsigned short As[32 * 64];    // 4 KB
  __shared__ unsigned short Bs[128 * 64];   // 16 KB
  int bid = blockIdx.x, tid = threadIdx.x;
  int t = bid >> 4, rem = bid & 15;
  int mt = rem >> 1, nt = rem & 1;
  int b0 = mt * 32, n0 = nt * 128;
  const unsigned short* abase = ((t < 16)
      ? st_out  + (size_t)t * 1048576
      : st_tail + (size_t)(t - 16) * 1048576) + (size_t)b0 * 4096;
  int w = RL(tid >> 6), l = tid & 63;
  int rh = w >> 1, chf = w & 1;

  int ar = tid >> 3, ac = tid & 7;
  unsigned short* adst = &As[ar * 64 + ((ac ^ (ar & 7)) << 3)];
  const unsigned short* asrc = abase + (size_t)ar * 4096 + (ac << 3);

  f32x4 acc[4];
  #pragma unroll
  for (int u = 0; u < 4; ++u) acc[u] = (f32x4){0.f, 0.f, 0.f, 0.f};

  for (int kt = 0; kt < 64; ++kt) {
    int k0 = kt * 64;
    __syncthreads();
    *(s16x8*)adst = *(const s16x8*)(asrc + k0);
    #pragma unroll
    for (int cc = 0; cc < 4; ++cc) {
      int idx = cc * 256 + tid;
      int br = idx >> 3, bc = idx & 7;
      *(s16x8*)&Bs[br * 64 + ((bc ^ (br & 7)) << 3)] =
          *(const s16x8*)(w1b + (size_t)(n0 + br) * 4096 + k0 + (bc << 3));
    }
    __syncthreads();
    #pragma unroll
    for (int kk = 0; kk < 2; ++kk) {
      int arw = rh * 16 + (l & 15);
      int chk = kk * 4 + (l >> 4);
      s16x8 av = *(const s16x8*)&As[arw * 64 + ((chk ^ (arw & 7)) << 3)];
      #pragma unroll
      for (int u = 0; u < 4; ++u) {
        int brow = (chf * 4 + u) * 16 + (l & 15);
        s16x8 bv = *(const s16x8*)&Bs[brow * 64 + ((chk ^ (brow & 7)) << 3)];
        acc[u] = __builtin_amdgcn_mfma_f32_16x16x32_bf16(av, bv, acc[u], 0, 0, 0);
      }
    }
  }
  float* pb = parts + (size_t)t * 65536;
  int colbase = n0 + chf * 64 + (l & 15);
  int rowbase = b0 + rh * 16 + (l >> 4) * 4;
  #pragma unroll
  for (int u = 0; u < 4; ++u)
    #pragma unroll
    for (int r = 0; r < 4; ++r)
      pb[(size_t)(rowbase + r) * 256 + colbase + u * 16] = acc[u][r];
}

// ---------------------------------------------------------------------------
// Full h2 pipeline: 256 blocks (1/batch) x 512 threads. FIRST pre-reduces the
// nslc split-K slices for THIS batch into LDS (parallel, coalesced, once).
// ---------------------------------------------------------------------------
__global__ __launch_bounds__(512, 1) void k_h2all(
    const float* __restrict__ partsk, int nslc,
    const float* __restrict__ w1b,
    const float* __restrict__ linT, const float* __restrict__ linb,
    const float* __restrict__ eps, float* __restrict__ scal,
    const float* __restrict__ dlinT, const float* __restrict__ dlinb,
    unsigned short* __restrict__ h2b)
{
  __shared__ float partsL[4864];             // 19 x 256 reduced h2h (19.4 KB)
  __shared__ float curL[256];
  __shared__ float ppart[512];
  __shared__ float red[256];
  int b = blockIdx.x, tid = threadIdx.x;
  const size_t SL = 1245184;
  // ---- one-shot parallel slice reduction for this batch ----
  for (int idx = tid; idx < 4864; idx += 512) {
    size_t off = (size_t)(idx >> 8) * 65536 + (size_t)b * 256 + (idx & 255);
    if (nslc == 8) {
      float s0 = partsk[off]          + partsk[SL + off];
      float s1 = partsk[2 * SL + off] + partsk[3 * SL + off];
      float s2 = partsk[4 * SL + off] + partsk[5 * SL + off];
      float s3 = partsk[6 * SL + off] + partsk[7 * SL + off];
      partsL[idx] = (s0 + s1) + (s2 + s3);
    } else {
      partsL[idx] = partsk[off];
    }
  }
  int o  = tid & 255, kh = tid >> 8;         // enc roles
  float wreg[128];
  #pragma unroll
  for (int jj = 0; jj < 128; ++jj)
    wreg[jj] = linT[(kh * 128 + jj) * 256 + o];
  __syncthreads();                           // partsL ready

  if (tid < 256)
    curL[tid] = relu_(partsL[tid] + w1b[tid]);
  __syncthreads();
  for (int t = 1; t <= 18; ++t) {
    float lacc = 0.f;
    #pragma unroll
    for (int jj = 0; jj < 128; ++jj)
      lacc += wreg[jj] * curL[kh * 128 + jj];   // LDS broadcast
    ppart[tid] = lacc;
    __syncthreads();                            // ppart ready; curL reads done
    if (tid < 256) {
      float h2h = relu_(partsL[t * 256 + tid] + w1b[tid]);
      curL[tid] = relu_(h2h + ppart[tid] + ppart[256 + tid] + linb[tid]);
    }
    __syncthreads();                            // curL ready for next step
  }
  if (tid < 128) {
    float mu = curL[tid], lv = curL[128 + tid];
    red[tid] = 0.5f * (expf(lv) + mu * mu - 1.0f - lv);
  }
  __syncthreads();
  for (int s = 64; s > 0; s >>= 1) {
    if (tid < s) red[tid] += red[tid + s];
    __syncthreads();
  }
  if (tid == 0) atomicAdd(&scal[1], red[0]);
  float hs = 0.f;
  if (tid < 128)
    hs = curL[tid] + expf(0.5f * curL[128 + tid]) * eps[(size_t)b * 128 + tid];
  __syncthreads();
  if (tid < 128) curL[tid] = hs;              // cur2 = h2s (128 entries)
  __syncthreads();

  int o2 = tid & 127, kh2 = (tid >> 7) & 1;
  float wreg2[64];
  if (tid < 256) {
    #pragma unroll
    for (int jj = 0; jj < 64; ++jj)
      wreg2[jj] = dlinT[(kh2 * 64 + jj) * 128 + o2];
  }
  for (int s = 0; s < 20; ++s) {
    if (tid < 256) {
      float lacc = 0.f;
      #pragma unroll
      for (int jj = 0; jj < 64; ++jj)
        lacc += wreg2[jj] * curL[kh2 * 64 + jj];
      ppart[tid] = lacc;
    }
    __syncthreads();                            // ppart ready; curL reads done
    if (tid < 128) {
      float v = relu_(ppart[tid] + ppart[128 + tid] + dlinb[tid]);
      h2b[(size_t)s * 32768 + (size_t)b * 128 + tid] = f2bf(v);
      curL[tid] = v;
    }
    __syncthreads();                            // curL ready for next step
  }
}

// ---------------------------------------------------------------------------
// VQ argmin quarters: grid 1024 (qtr = bid>>8, b = bid&255), from fp32 h1_18.
// ---------------------------------------------------------------------------
__global__ __launch_bounds__(256) void k_argmin(
    const float* __restrict__ h1f, const float* __restrict__ emb,
    const float* __restrict__ embsq,
    float* __restrict__ pbest, int* __restrict__ pidx)
{
  __shared__ float sd[256];
  __shared__ int   sk[256];
  int bid = blockIdx.x, tid = threadIdx.x;
  int qtr = bid >> 8, b = bid & 255;
  int p = tid & 63, kg = RL(tid >> 6);
  float f[64];
  const float* hb = h1f + (size_t)b * 4096 + p;
  #pragma unroll
  for (int c = 0; c < 64; ++c) f[c] = hb[c * 64];
  float best = 3.4e38f; int bk = 0;
  int kbeg = qtr * 128 + kg * 32;
  for (int k = kbeg; k < kbeg + 32; ++k) {
    const float* er = emb + k * 64;            // uniform -> s_load
    float d0 = 0, d1 = 0, d2 = 0, d3 = 0;
    #pragma unroll
    for (int c = 0; c < 64; c += 4) {
      d0 += f[c] * er[c];     d1 += f[c+1] * er[c+1];
      d2 += f[c+2] * er[c+2]; d3 += f[c+3] * er[c+3];
    }
    float d = embsq[k] - 2.f * ((d0 + d1) + (d2 + d3));
    if (d < best) { best = d; bk = k; }
  }
  sd[tid] = best; sk[tid] = bk;
  __syncthreads();
  if (tid < 64) {
    float bb = sd[tid]; int kk = sk[tid];
    #pragma unroll
    for (int g = 1; g < 4; ++g) {
      float dg = sd[g * 64 + tid];
      if (dg < bb) { bb = dg; kk = sk[g * 64 + tid]; }
    }
    pbest[qtr * 16384 + b * 64 + tid] = bb;
    pidx [qtr * 16384 + b * 64 + tid] = kk;
  }
}

// ---------------------------------------------------------------------------
// h1l placement: step d's projection, bf16.
// ---------------------------------------------------------------------------
__device__ __forceinline__ unsigned short* h1l_ptr(
    int d, int b, float* out, unsigned short* tail)
{
  if (d >= 1 && d <= 17)
    return (unsigned short*)(out + 2 + (size_t)b * 32832 + (size_t)(d - 1) * 1728);
  int slot = (d == 0) ? 0 : (d - 17);
  return tail + (size_t)slot * 1048576 + (size_t)b * 4096;
}

// ---------------------------------------------------------------------------
// MFMA h1l: h1l[d*256+b][n] = sum_j h2b[d*256+b][j] * dw1b[n][j], bf16 out.
// ---------------------------------------------------------------------------
__global__ __launch_bounds__(256) void k_declmma(
    const unsigned short* __restrict__ h2b,
    const unsigned short* __restrict__ dw1b,
    float* __restrict__ out, unsigned short* __restrict__ tail)
{
  __shared__ unsigned short As[64 * 128];   // 16 KB
  __shared__ unsigned short Bs[64 * 128];   // 16 KB
  int bid = blockIdx.x, tid = threadIdx.x;
  int mt = bid >> 6, nt = bid & 63;
  int m0 = mt * 64, n0 = nt * 64;
  int w = RL(tid >> 6), l = tid & 63;

  #pragma unroll
  for (int cc = 0; cc < 4; ++cc) {
    int idx = cc * 256 + tid;
    int row = idx >> 4, col = idx & 15;
    *(s16x8*)&As[row * 128 + ((col ^ (row & 7)) << 3)] =
        *(const s16x8*)(h2b + (size_t)(m0 + row) * 128 + (col << 3));
    *(s16x8*)&Bs[row * 128 + ((col ^ (row & 7)) << 3)] =
        *(const s16x8*)(dw1b + (size_t)(n0 + row) * 128 + (col << 3));
  }
  __syncthreads();

  f32x4 acc[4];
  #pragma unroll
  for (int u = 0; u < 4; ++u) acc[u] = (f32x4){0.f, 0.f, 0.f, 0.f};
  int arow = w * 16 + (l & 15);
  #pragma unroll
  for (int kk = 0; kk < 4; ++kk) {
    int chk = kk * 4 + (l >> 4);
    s16x8 av = *(const s16x8*)&As[arow * 128 + ((chk ^ (arow & 7)) << 3)];
    #pragma unroll
    for (int u = 0; u < 4; ++u) {
      int brow = u * 16 + (l & 15);
      s16x8 bv = *(const s16x8*)&Bs[brow * 128 + ((chk ^ (brow & 7)) << 3)];
      acc[u] = __builtin_amdgcn_mfma_f32_16x16x32_bf16(av, bv, acc[u], 0, 0, 0);
    }
  }
  int d = m0 >> 8;                        // uniform per block
  #pragma unroll
  for (int r = 0; r < 4; ++r) {
    int b = (m0 & 255) + w * 16 + (l >> 4) * 4 + r;
    unsigned short* op = h1l_ptr(d, b, out, tail);
    #pragma unroll
    for (int u = 0; u < 4; ++u)
      op[n0 + u * 16 + (l & 15)] = f2bf(acc[u][r]);
  }
}

// ---------------------------------------------------------------------------
// VQ stats: grid 256 (one batch): merge quarters, Q, loss, histogram.
// ---------------------------------------------------------------------------
__global__ __launch_bounds__(256) void k_vqstats(
    const float* __restrict__ h1f, const float* __restrict__ emb,
    const float* __restrict__ pbest, const int* __restrict__ pidx,
    float* __restrict__ Q, float* __restrict__ counts,
    float* __restrict__ loss_sum)
{
  __shared__ int   fk[64];
  __shared__ int   lhist[512];
  __shared__ float red[256];
  int b = blockIdx.x, tid = threadIdx.x;
  for (int j = tid; j < 512; j += 256) lhist[j] = 0;
  __syncthreads();
  if (tid < 64) {
    float bb = pbest[b * 64 + tid];
    int   kk = pidx [b * 64 + tid];
    #pragma unroll
    for (int q = 1; q < 4; ++q) {
      float dq = pbest[q * 16384 + b * 64 + tid];
      if (dq < bb) { bb = dq; kk = pidx[q * 16384 + b * 64 + tid]; }
    }
    fk[tid] = kk;
    atomicAdd(&lhist[kk], 1);
  }
  __syncthreads();
  int p = tid & 63, cgi = tid >> 6;
  int kk = fk[p];
  const float* eb = emb + kk * 64 + cgi * 16;
  const float* hz = h1f + (size_t)b * 4096 + cgi * 1024 + p;
  float* qb = Q + (size_t)b * 4096 + cgi * 1024 + p;
  float ls = 0;
  #pragma unroll
  for (int c = 0; c < 16; ++c) {
    float e = eb[c];
    float z = hz[c * 64];
    float dd = e - z;
    ls += dd * dd;
    qb[c * 64] = e;
  }
  red[tid] = ls;
  __syncthreads();
  for (int s = 128; s > 0; s >>= 1) { if (tid < s) red[tid] += red[tid + s]; __syncthreads(); }
  if (tid == 0) atomicAdd(loss_sum, red[0]);
  for (int j = tid; j < 512; j += 256) {
    int h = lhist[j];
    if (h > 0) atomicAdd(&counts[j], (float)h);
  }
}

// ---------------------------------------------------------------------------
// Decoder chain, MFMA edition. 256 blocks (one batch) x 1024 thr = 16 waves:
//  waves 0..7  : state update Hnew = relu(dr0 . H + h1l + bias) via MFMA
//                [setprio(1) around the chain-critical phase -- T5 role-split]
//  waves 8..15 : frame emit y = w0d^T . H via MFMA, one iteration behind
// Block 256 finalizes scalars.
// ---------------------------------------------------------------------------
__global__ __launch_bounds__(1024) void k_decchain(
    const float* __restrict__ Q,
    const float* __restrict__ dr0, const float* __restrict__ dr0b,
    const float* __restrict__ dw1b_bias,
    const float* __restrict__ w0d, const float* __restrict__ w0db,
    float* __restrict__ out, unsigned short* __restrict__ tail,
    const float* __restrict__ counts, const float* __restrict__ scal)
{
  int bid = blockIdx.x, tid = threadIdx.x;
  if (bid == 256) {            // ---- finalize ----
    __shared__ float red[512];
    if (tid < 512) {
      float avg = counts[tid] * (1.0f / 16384.0f);
      red[tid] = avg * logf(avg + 1e-10f);
    }
    __syncthreads();
    for (int s = 256; s > 0; s >>= 1) {
      if (tid < s) red[tid] += red[tid + s];
      __syncthreads();
    }
    if (tid == 0) {
      out[0] = 0.25f * scal[0] * (1.0f / 1048576.0f);
      out[1] = scal[1] * (1.0f / 256.0f);
      out[2 + 8404992] = expf(-red[0]);
    }
    return;
  }
  __shared__ unsigned short Hs[2][4096];   // [p][c] bf16, 16B-chunk XOR swizzle
  int b = bid;
  int l = tid & 63;
  int wv = RL(tid >> 6);

  for (int idx = tid; idx < 4096; idx += 1024) {
    int c = idx >> 6, p = idx & 63;
    Hs[0][p * 64 + ((((c >> 3) ^ (p & 7))) << 3) + (c & 7)] =
        f2bf(Q[(size_t)b * 4096 + idx]);
  }

  if (wv < 8) {
    // ---------------- update waves ----------------
    int os = wv >> 1;                    // o-strip 0..3
    int ph = wv & 1;                     // p-half 0..1
    int co = os * 16 + (l >> 4) * 4;     // acc row base (o)
    int arow = os * 16 + (l & 15);       // A-frag row
    s16x8 avR[2];
    #pragma unroll
    for (int kk = 0; kk < 2; ++kk) {
      int cb = (kk * 4 + (l >> 4)) * 8;
      const float* src = dr0 + arow * 64 + cb;
      #pragma unroll
      for (int j = 0; j < 8; ++j) avR[kk][j] = (short)f2bf(src[j]);
    }
    float biasv[4];
    #pragma unroll
    for (int r = 0; r < 4; ++r) biasv[r] = dr0b[co + r] + dw1b_bias[co + r];
    int pA = (ph * 2) * 16 + (l & 15);
    int pB = (ph * 2 + 1) * 16 + (l & 15);
    __syncthreads();

    for (int i = 0; i <= 20; ++i) {
      if (i <= 19) {
        __builtin_amdgcn_s_setprio(1);   // favor update waves vs emit waves
        const unsigned short* lp = h1l_ptr(i, b, out, tail);
        float hlA[4], hlB[4];
        #pragma unroll
        for (int r = 0; r < 4; ++r) {
          hlA[r] = bf2f(lp[(co + r) * 64 + pA]);
          hlB[r] = bf2f(lp[(co + r) * 64 + pB]);
        }
        const unsigned short* cb = Hs[i & 1];
        f32x4 accA = (f32x4){0.f, 0.f, 0.f, 0.f};
        f32x4 accB = (f32x4){0.f, 0.f, 0.f, 0.f};
        #pragma unroll
        for (int kk = 0; kk < 2; ++kk) {
          int chk = kk * 4 + (l >> 4);
          s16x8 bvA = *(const s16x8*)&cb[pA * 64 + ((chk ^ (pA & 7)) << 3)];
          s16x8 bvB = *(const s16x8*)&cb[pB * 64 + ((chk ^ (pB & 7)) << 3)];
          accA = __builtin_amdgcn_mfma_f32_16x16x32_bf16(avR[kk], bvA, accA, 0, 0, 0);
          accB = __builtin_amdgcn_mfma_f32_16x16x32_bf16(avR[kk], bvB, accB, 0, 0, 0);
        }
        unsigned short* nb = Hs[(i + 1) & 1];
        {
          float v0 = relu_(accA[0] + hlA[0] + biasv[0]);
          float v1 = relu_(accA[1] + hlA[1] + biasv[1]);
          float v2 = relu_(accA[2] + hlA[2] + biasv[2]);
          float v3 = relu_(accA[3] + hlA[3] + biasv[3]);
          uint2 pk;
          pk.x = (unsigned)f2bf(v0) | ((unsigned)f2bf(v1) << 16);
          pk.y = (unsigned)f2bf(v2) | ((unsigned)f2bf(v3) << 16);
          *(uint2*)&nb[pA * 64 + (((co >> 3) ^ (pA & 7)) << 3) + (co & 7)] = pk;
        }
        {
          float v0 = relu_(accB[0] + hlB[0] + biasv[0]);
          float v1 = relu_(accB[1] + hlB[1] + biasv[1]);
          float v2 = relu_(accB[2] + hlB[2] + biasv[2]);
          float v3 = relu_(accB[3] + hlB[3] + biasv[3]);
          uint2 pk;
          pk.x = (unsigned)f2bf(v0) | ((unsigned)f2bf(v1) << 16);
          pk.y = (unsigned)f2bf(v2) | ((unsigned)f2bf(v3) << 16);
          *(uint2*)&nb[pB * 64 + (((co >> 3) ^ (pB & 7)) << 3) + (co & 7)] = pk;
        }
        __builtin_amdgcn_s_setprio(0);
      }
      __syncthreads();
    }
  } else {
    // ---------------- emit waves ----------------
    int job = wv - 8;
    int mt = job >> 2, pt = job & 3;
    int m0 = mt * 16 + (l >> 4) * 4;     // acc row base (m)
    int am = mt * 16 + (l & 15);         // A-frag row
    s16x8 avE[2];
    #pragma unroll
    for (int kk = 0; kk < 2; ++kk) {
      int cbg = (kk * 4 + (l >> 4)) * 8;
      #pragma unroll
      for (int j = 0; j < 8; ++j)
        avE[kk][j] = (am < 27) ? (short)f2bf(w0d[(cbg + j) * 27 + am]) : (short)0;
    }
    int p = pt * 16 + (l & 15);
    int hrow = p >> 3, wcol = p & 7;
    int preoff[4]; float eb[4]; bool vld[4];
    #pragma unroll
    for (int r = 0; r < 4; ++r) {
      int m = m0 + r;
      vld[r] = (m < 27);
      int mm = vld[r] ? m : 0;
      int o3 = mm / 9, rr = mm % 9, ki = rr / 3, kj = rr % 3;
      preoff[r] = o3 * 576 + (hrow * 3 + ki) * 24 + wcol * 3 + kj;
      eb[r] = w0db[o3];
    }
    __syncthreads();

    for (int i = 0; i <= 20; ++i) {
      if (i >= 2) {
        const unsigned short* cb = Hs[i & 1];
        f32x4 acc = (f32x4){0.f, 0.f, 0.f, 0.f};
        #pragma unroll
        for (int kk = 0; kk < 2; ++kk) {
          int chk = kk * 4 + (l >> 4);
          s16x8 bv = *(const s16x8*)&cb[p * 64 + ((chk ^ (p & 7)) << 3)];
          acc = __builtin_amdgcn_mfma_f32_16x16x32_bf16(avE[kk], bv, acc, 0, 0, 0);
        }
        int t = i - 2;
        float* fb = out + 2 + (size_t)(b * 19 + t) * 1728;
        #pragma unroll
        for (int r = 0; r < 4; ++r) {
          if (vld[r]) {
            float v = acc[r] + eb[r];
            v = v > 0.f ? v : expm1f(v);             // ELU alpha=1
            fb[preoff[r]] = v;
          }
        }
      }
      __syncthreads();
    }
  }
}

// ---------------------------------------------------------------------------
extern "C" void kernel_launch(void* const* d_in, const int* in_sizes, int n_in,
                              void* d_out, int out_size, void* d_ws, size_t ws_size,
                              hipStream_t stream)
{
  const float* x     = (const float*)d_in[0];
  const float* eps   = (const float*)d_in[1];
  const float* emb   = (const float*)d_in[2];
  const float* ew0   = (const float*)d_in[3];
  const float* ew0b  = (const float*)d_in[4];
  const float* ew1   = (const float*)d_in[5];
  const float* ew1b  = (const float*)d_in[6];
  const float* er0   = (const float*)d_in[7];
  const float* er0b  = (const float*)d_in[8];
  const float* elinw = (const float*)d_in[9];
  const float* elinb = (const float*)d_in[10];
  const float* dw0   = (const float*)d_in[11];
  const float* dw0b  = (const float*)d_in[12];
  const float* dw1   = (const float*)d_in[13];
  const float* dw1b  = (const float*)d_in[14];
  const float* dr0   = (const float*)d_in[15];
  const float* dr0b  = (const float*)d_in[16];
  const float* dlinw = (const float*)d_in[17];
  const float* dlinb = (const float*)d_in[18];
  float* out = (float*)d_out;
  float* ws  = (float*)d_ws;

  // ws layout (floats): base ~22.6 MB; split-K partials (40 MB) appended.
  unsigned short* W1B = (unsigned short*)ws;  // 256x4096 bf16; Q overlays
  float* Q      = ws + 0;          // 256x4096 fp32
  float* LINT   = ws + 1048576;    // 256x256 (j-major)
  float* DLINT  = ws + 1114112;    // 128x128 (j-major)
  float* EMBSQ  = ws + 1130496;    // 512
  float* H1F    = ws + 1131008;    // 256x4096 fp32 h1_18
  float* PARTS  = ws + 2179584;    // 19x256x256 (fallback contract output)
  float* PBEST  = ws + 2179584;    // overlays PARTS (argmin after h2all)
  int*   PIDX   = (int*)(ws + 2245120);
  unsigned short* TAIL = (unsigned short*)(ws + 3424768); // 3x1,048,576 bf16
  unsigned short* H2B  = (unsigned short*)(ws + 4997632); // 5120x128 bf16
  unsigned short* DW1B = (unsigned short*)(ws + 5325312); // 4096x128 bf16
  float* SCAL   = ws + 5652992;    // [0]=loss, [1]=kl
  float* COUNTS = ws + 5652994;    // 512
  const size_t XC_OFF = 5653508;   // 16B-aligned; split-K partial region
  const size_t XC_END = XC_OFF + (size_t)8 * 1245184;  // 8 slices, ~40 MB
  bool big = ws_size >= XC_END * sizeof(float);
  float* PARTSK = big ? (ws + XC_OFF) : nullptr;

  unsigned short* ST_OUT = (unsigned short*)(out + 2);  // 16 bf16 h1 states

  k_prep<<<213, 256, 0, stream>>>(ew1, elinw, dlinw, emb, dw1, W1B, LINT,
                                  DLINT, EMBSQ, DW1B, SCAL, COUNTS);
  k_encmma<<<256, 1024, 0, stream>>>(x, ew0, ew0b, er0, er0b,
                                     ST_OUT, TAIL, H1F);
  const float* parts_src;
  int nslc;
  if (big) {
    k_conmma8<<<2432, 256, 0, stream>>>(ST_OUT, TAIL, W1B, PARTSK);
    parts_src = PARTSK; nslc = 8;
  } else {
    k_conmma<<<304, 256, 0, stream>>>(ST_OUT, TAIL, W1B, PARTS);
    parts_src = PARTS; nslc = 1;
  }
  k_h2all<<<256, 512, 0, stream>>>(parts_src, nslc, ew1b, LINT, elinb, eps,
                                   SCAL, DLINT, dlinb, H2B);
  k_argmin<<<1024, 256, 0, stream>>>(H1F, emb, EMBSQ, PBEST, PIDX);
  k_declmma<<<5120, 256, 0, stream>>>(H2B, DW1B, out, TAIL);
  k_vqstats<<<256, 256, 0, stream>>>(H1F, emb, PBEST, PIDX, Q, COUNTS,
                                     &SCAL[0]);
  k_decchain<<<257, 1024, 0, stream>>>(Q, dr0, dr0b, dw1b, dw0, dw0b,
                                       out, TAIL, COUNTS, SCAL);
}